// Round 3
// baseline (331.781 us; speedup 1.0000x reference)
//
#include <hip/hip_runtime.h>
#include <hip/hip_fp16.h>

// 3-layer gather-GEMM GNN (N=262144, K=8, 16->128->128->16), f16 MFMA.
// Round 15: r14 hit its (256,4) reg cap and spilled (~9 dwords/thread:
// WRITE_SIZE 65.5->102.4 MB = scratch writeback). Fix: delete the Bn
// prefetch ring entirely (16 regs + 32 v_movs/iter). W1f is L2-resident
// (256 KB, read by every block) and plain global->VGPR loads schedule
// freely within the iteration; TLP at 16 waves/CU covers ~200cy L2 latency.
// MFMA accumulation order per accumulator unchanged -> bit-identical.
//   * ga[2][4] reg-staged gather ring (crosses barriers, depth 2) — kept.
//   * Bc loaded directly per half-phase, no ring.
//   * roff4 / on-demand invd scalars / 2-slot idxQ — kept from r14.
//   * __launch_bounds__(256, 4): 4 blocks/CU, LDS 4x32KB = 128 KB.
//
// Workspace: ws = h1 (64 MiB) + P (64 MiB) = 128 MiB exactly. invd/h16/Wf live
// in d_out scratch; invd is d2d-copied into dead h1 before the reduce (which
// writes d_out).

typedef _Float16 f16x8 __attribute__((ext_vector_type(8)));
typedef float f32x4 __attribute__((ext_vector_type(4)));

#define NNODES 262144

__global__ __launch_bounds__(256) void conv_h_kernel(const float* __restrict__ h,
                                                     __half* __restrict__ h16, int n) {
    int i = blockIdx.x * 256 + threadIdx.x;
    if (i < n) h16[i] = __float2half(h[i]);
}

__global__ __launch_bounds__(256) void prep_edges_kernel(const float* __restrict__ pos,
                                                         const int* __restrict__ nbr,
                                                         __half* __restrict__ invd, int n_edges) {
    int e = blockIdx.x * 256 + threadIdx.x;
    if (e >= n_edges) return;
    int i = e >> 3;
    int n = nbr[e];
    float dx = pos[i * 3 + 0] - pos[n * 3 + 0];
    float dy = pos[i * 3 + 1] - pos[n * 3 + 1];
    float dz = pos[i * 3 + 2] - pos[n * 3 + 2];
    float d = sqrtf(dx * dx + dy * dy + dz * dz);
    if (d == 0.0f) d = 0.5f;                       // reference: where(dist==0, 0.5, dist)
    invd[e] = __float2half((1.0f / d) * 0.00390625f);  // prescale 1/256
}

// Pre-shuffle W [KT][FO] (row-major f32) into MFMA B-fragment order:
// Wf[((s*NT + t)*64 + lane)*8 + j] = W[s*32 + (lane>>4)*8 + j][t*16 + (lane&15)]
__global__ __launch_bounds__(256) void shuffle_w_kernel(const float* __restrict__ W,
                                                        __half* __restrict__ Wf,
                                                        int KT, int FO) {
    int e = blockIdx.x * 256 + threadIdx.x;
    if (e >= KT * FO) return;
    int j = e & 7;
    int lane = (e >> 3) & 63;
    int rest = e >> 9;
    int NT = FO >> 4;
    int t = rest % NT;
    int s = rest / NT;
    int k = s * 32 + (lane >> 4) * 8 + j;
    int n = t * 16 + (lane & 15);
    Wf[e] = __float2half(W[k * FO + n]);
}

// Fragment-order for the STACKED W2: W2s[k][t*16+c] = W2[t*128+k][c]
// (W2 row-major [1024][16]; KT=128, FO=128 -> NT=8).
__global__ __launch_bounds__(256) void shuffle_w2s_kernel(const float* __restrict__ W2,
                                                          __half* __restrict__ Wf) {
    int e = blockIdx.x * 256 + threadIdx.x;
    if (e >= 128 * 128) return;
    int j = e & 7;
    int lane = (e >> 3) & 63;
    int rest = e >> 9;
    int t = rest % 8;
    int s = rest / 8;
    int k = s * 32 + (lane >> 4) * 8 + j;
    Wf[e] = __float2half(W2[(size_t)(t * 128 + k) * 16 + (lane & 15)]);
}

// ---------------- L0: F_IN=16, F_OUT=128, 128 rows/block ----------------
__global__ __launch_bounds__(256) void layer0_kernel(
    const __half* __restrict__ hprev, const __half* __restrict__ invd,
    const int* __restrict__ nbr, const __half* __restrict__ Wf,
    const float* __restrict__ bias, __half* __restrict__ outp) {
    __shared__ __align__(16) __half Bs[16384];  // 32 KB weights, staged once

    const int tid = threadIdx.x;
    const int wave = tid >> 6;
    const int lane = tid & 63;
    const int quad = lane >> 4;
    const int lmod = lane & 15;
    const int mbase = blockIdx.x * 128 + wave * 16 + lmod;

    int idx[2][8];
    f16x8 invr[2];
#pragma unroll
    for (int mt = 0; mt < 2; ++mt) {
        const int m = mbase + mt * 64;
        const int4* nrow = (const int4*)(nbr + (size_t)m * 8);
        const int4 iA = nrow[0];
        const int4 iB = nrow[1];
        idx[mt][0] = iA.x; idx[mt][1] = iA.y; idx[mt][2] = iA.z; idx[mt][3] = iA.w;
        idx[mt][4] = iB.x; idx[mt][5] = iB.y; idx[mt][6] = iB.z; idx[mt][7] = iB.w;
        invr[mt] = *(const f16x8*)(invd + (size_t)m * 8);
    }

    f32x4 acc[2][8];
#pragma unroll
    for (int mt = 0; mt < 2; ++mt)
#pragma unroll
        for (int t = 0; t < 8; ++t) acc[mt][t] = f32x4{0.f, 0.f, 0.f, 0.f};

    {
        const uint4* src = (const uint4*)Wf;
        uint4* dst = (uint4*)Bs;
#pragma unroll
        for (int i = 0; i < 8; ++i) dst[i * 256 + tid] = src[i * 256 + tid];
    }
    __syncthreads();

#pragma unroll
    for (int s = 0; s < 4; ++s) {
        const int nb = 2 * s + (quad >> 1);
        f16x8 as[2];
#pragma unroll
        for (int mt = 0; mt < 2; ++mt) {
            f16x8 av = *(const f16x8*)(hprev + (size_t)idx[mt][nb] * 16 + (quad & 1) * 8);
            as[mt] = av * invr[mt][nb];
        }
#pragma unroll
        for (int t = 0; t < 8; ++t) {
            f16x8 b = *(const f16x8*)(Bs + ((size_t)(s * 8 + t) * 64 + lane) * 8);
#pragma unroll
            for (int mt = 0; mt < 2; ++mt)
                acc[mt][t] = __builtin_amdgcn_mfma_f32_16x16x32_f16(as[mt], b, acc[mt][t], 0, 0, 0);
        }
    }

#pragma unroll
    for (int mt = 0; mt < 2; ++mt) {
        const int rbase = blockIdx.x * 128 + mt * 64 + wave * 16 + quad * 4;
#pragma unroll
        for (int t = 0; t < 8; ++t) {
            const int col = t * 16 + lmod;
            const float bv = bias[col];
#pragma unroll
            for (int rr = 0; rr < 4; ++rr) {
                float v = acc[mt][t][rr] * 256.0f + bv;
                outp[(size_t)(rbase + rr) * 128 + col] = __float2half(v);
            }
        }
    }
}

// ------- L1+P: F_IN=128, F_OUT=128, 64 rows/block, fused P projection -------
// LDS: seg-major + XOR swizzle, 16B granules: off16(seg,row) =
//   seg*64 + (row & ~15) + ((row ^ seg) & 15)   -> spans [0, 1024) granules.
__device__ __forceinline__ int off16(int seg, int row) {
    return seg * 64 + (row & ~15) + ((row ^ seg) & 15);
}

__global__ __launch_bounds__(256, 4) void layer1p_kernel(
    const __half* __restrict__ hprev, const __half* __restrict__ invd,
    const int* __restrict__ nbr, const __half* __restrict__ Wf,
    const __half* __restrict__ Wf2s, const float* __restrict__ bias,
    __half* __restrict__ Pout) {
    __shared__ __align__(16) __half As[2][8192];  // 2 x 1024 granules x 16B = 32 KB

    const int tid = threadIdx.x;
    const int wave = tid >> 6;
    const int lane = tid & 63;
    const int quad = lane >> 4;
    const int lmod = lane & 15;
    const int rowblk = blockIdx.x * 64;
    const int seg = lmod;  // staging: this thread's 16B segment

    // Thread's 4 staged rows: srow(i) = wave*16 + i*4 + quad; global row
    // rbase + i*4 with rbase = rowblk + wave*16 + quad.  nbr/invd rows for
    // (i, nb) sit at base + i*32 + nb -> one base pointer, imm offsets.
    const int rbase = rowblk + wave * 16 + quad;
    const int* nbp = nbr + (size_t)rbase * 8;
    const __half* ivp = invd + (size_t)rbase * 8;

    int soff[4];
#pragma unroll
    for (int i = 0; i < 4; ++i) {
        const int srow = wave * 16 + i * 4 + quad;
        soff[i] = off16(seg, srow) * 8;  // halves
    }

    // Fragment-read offsets (halves): off16(ks*4+quad, m*16+lmod)*8 =
    // roff4[ks] + m*128.
    int roff4[4];
#pragma unroll
    for (int ks = 0; ks < 4; ++ks) {
        const int sg = ks * 4 + quad;
        roff4[ks] = (sg * 64 + ((lmod ^ sg) & 15)) * 8;
    }

    // This wave's two output col-tiles: t = wave*2 + tl.
    const __half* WfB = Wf + ((size_t)(wave * 2) * 64 + lane) * 8;

    // 2-deep gather ring (global->VGPR loads cross barriers) + 2-slot idx ring.
    int idxQ[2][4];
    f16x8 ga[2][4];
    {
        int id0[4], id1[4];
#pragma unroll
        for (int i = 0; i < 4; ++i) id0[i] = nbp[i * 32 + 0];
#pragma unroll
        for (int i = 0; i < 4; ++i)
            ga[0][i] = *(const f16x8*)(hprev + (size_t)id0[i] * 128 + seg * 8);
#pragma unroll
        for (int i = 0; i < 4; ++i) id1[i] = nbp[i * 32 + 1];
#pragma unroll
        for (int i = 0; i < 4; ++i)
            ga[1][i] = *(const f16x8*)(hprev + (size_t)id1[i] * 128 + seg * 8);
#pragma unroll
        for (int i = 0; i < 4; ++i) idxQ[0][i] = nbp[i * 32 + 2];
#pragma unroll
        for (int i = 0; i < 4; ++i) idxQ[1][i] = nbp[i * 32 + 3];
    }

    // Stage neighbor 0 (scaled) into As[0].
#pragma unroll
    for (int i = 0; i < 4; ++i) {
        const _Float16 sc = *(const _Float16*)(ivp + i * 32 + 0);
        f16x8 v = ga[0][i] * sc;
        *(f16x8*)(&As[0][soff[i]]) = v;
    }
    __syncthreads();

    f32x4 acc[4][2];
#pragma unroll
    for (int m = 0; m < 4; ++m) { acc[m][0] = f32x4{0.f,0.f,0.f,0.f}; acc[m][1] = f32x4{0.f,0.f,0.f,0.f}; }

#pragma unroll
    for (int nb = 0; nb < 8; ++nb) {
        const int cur = nb & 1;
        // Issue gathers for neighbor nb+2 into ga[cur] (slot's old data =
        // neighbor nb, staged at end of iter nb-1).  Crosses barriers freely.
        if (nb < 6) {
#pragma unroll
            for (int i = 0; i < 4; ++i)
                ga[cur][i] = *(const f16x8*)(hprev + (size_t)idxQ[cur][i] * 128 + seg * 8);
        }
        // Refill idx ring: neighbor nb+4 into the slot just consumed.
        if (nb < 4) {
#pragma unroll
            for (int i = 0; i < 4; ++i)
                idxQ[cur][i] = nbp[i * 32 + nb + 4];
        }
        // Compute from As[cur]: two half-phases; B frags loaded directly
        // (W1f is L2-hot; loads hoist within the iteration, TLP covers).
#pragma unroll
        for (int h = 0; h < 2; ++h) {
            f16x8 Bc[2][2];
#pragma unroll
            for (int ks2 = 0; ks2 < 2; ++ks2)
#pragma unroll
                for (int tl = 0; tl < 2; ++tl)
                    Bc[ks2][tl] = *(const f16x8*)(WfB + (size_t)((nb * 4 + h * 2 + ks2) * 8 + tl) * 512);
#pragma unroll
            for (int m = 0; m < 4; ++m) {
#pragma unroll
                for (int ks2 = 0; ks2 < 2; ++ks2) {
                    f16x8 a = *(const f16x8*)(&As[cur][roff4[h * 2 + ks2] + m * 128]);
                    acc[m][0] = __builtin_amdgcn_mfma_f32_16x16x32_f16(a, Bc[ks2][0], acc[m][0], 0, 0, 0);
                    acc[m][1] = __builtin_amdgcn_mfma_f32_16x16x32_f16(a, Bc[ks2][1], acc[m][1], 0, 0, 0);
                }
            }
        }
        // Stage neighbor nb+1 (scaled) into As[cur^1], then barrier.
        if (nb < 7) {
#pragma unroll
            for (int i = 0; i < 4; ++i) {
                const _Float16 sc = *(const _Float16*)(ivp + i * 32 + nb + 1);
                f16x8 v = ga[(nb + 1) & 1][i] * sc;
                *(f16x8*)(&As[cur ^ 1][soff[i]]) = v;
            }
            __syncthreads();
        }
    }

    // ---- Fused epilogue: h2 = leaky(acc*256 + b1) -> LDS (swizzled) ----
    // As[0] is free: its last reader was nb=6's compute, before the last
    // barrier. h2 tile = 64 rows x 128 cols, element (row,col) at granule
    // off16(col>>3, row), half (col&7).
    __half* As0 = &As[0][0];
#pragma unroll
    for (int m = 0; m < 4; ++m) {
#pragma unroll
        for (int tl = 0; tl < 2; ++tl) {
            const int col = wave * 32 + tl * 16 + lmod;
            const float bv = bias[col];
            const int sg = col >> 3;
            const int jj = col & 7;
#pragma unroll
            for (int rr = 0; rr < 4; ++rr) {
                const int row = m * 16 + quad * 4 + rr;
                float v = acc[m][tl][rr] * 256.0f + bv;
                v = (v >= 0.f) ? v : 0.01f * v;
                As0[off16(sg, row) * 8 + jj] = __float2half(v);
            }
        }
    }
    __syncthreads();

    // ---- P = h2 @ W2s (K=128, 4 k-steps); wave owns col-tiles wave*2+tl ----
    const __half* WfB2 = Wf2s + ((size_t)(wave * 2) * 64 + lane) * 8;
    f16x8 B2[4][2];
#pragma unroll
    for (int ks = 0; ks < 4; ++ks)
#pragma unroll
        for (int tl = 0; tl < 2; ++tl)
            B2[ks][tl] = *(const f16x8*)(WfB2 + (size_t)(ks * 8 + tl) * 512);

    f32x4 acc2[4][2];
#pragma unroll
    for (int m = 0; m < 4; ++m) { acc2[m][0] = f32x4{0.f,0.f,0.f,0.f}; acc2[m][1] = f32x4{0.f,0.f,0.f,0.f}; }
#pragma unroll
    for (int m = 0; m < 4; ++m) {
#pragma unroll
        for (int ks = 0; ks < 4; ++ks) {
            f16x8 a2 = *(const f16x8*)(&As0[roff4[ks] + m * 128]);
            acc2[m][0] = __builtin_amdgcn_mfma_f32_16x16x32_f16(a2, B2[ks][0], acc2[m][0], 0, 0, 0);
            acc2[m][1] = __builtin_amdgcn_mfma_f32_16x16x32_f16(a2, B2[ks][1], acc2[m][1], 0, 0, 0);
        }
    }

    // ---- write P (fp16, true scale) ----
#pragma unroll
    for (int m = 0; m < 4; ++m) {
#pragma unroll
        for (int tl = 0; tl < 2; ++tl) {
            const int col = wave * 32 + tl * 16 + lmod;
#pragma unroll
            for (int rr = 0; rr < 4; ++rr) {
                const int grow = rowblk + m * 16 + quad * 4 + rr;
                Pout[(size_t)grow * 128 + col] = __float2half(acc2[m][tl][rr]);
            }
        }
    }
}

// ---------------- Reduce: out[i] = 256*sum_k invd[i,k]*P[nbr[i,k]][k*16..]+b2
__global__ __launch_bounds__(256) void reduce_kernel(
    const __half* __restrict__ P, const __half* __restrict__ invd,
    const int* __restrict__ nbr, const float* __restrict__ b2,
    float* __restrict__ outp) {
    const int d = blockIdx.x * 256 + threadIdx.x;

    const int4* nrow = (const int4*)(nbr + (size_t)d * 8);
    const int4 iA = nrow[0];
    const int4 iB = nrow[1];
    const int idx[8] = {iA.x, iA.y, iA.z, iA.w, iB.x, iB.y, iB.z, iB.w};
    const f16x8 iv = *(const f16x8*)(invd + (size_t)d * 8);

    // Issue all 16 gather loads up front.
    f16x8 lo[8], hi[8];
#pragma unroll
    for (int k = 0; k < 8; ++k) {
        const __half* p = P + (size_t)idx[k] * 128 + k * 16;
        lo[k] = *(const f16x8*)p;
        hi[k] = *(const f16x8*)(p + 8);
    }

    float acc[16];
#pragma unroll
    for (int c = 0; c < 16; ++c) acc[c] = 0.f;
#pragma unroll
    for (int k = 0; k < 8; ++k) {
        const float w = (float)iv[k];
#pragma unroll
        for (int c = 0; c < 8; ++c) {
            acc[c] += w * (float)lo[k][c];
            acc[c + 8] += w * (float)hi[k][c];
        }
    }

    float4 o[4];
#pragma unroll
    for (int q = 0; q < 4; ++q) {
        o[q].x = acc[q * 4 + 0] * 256.0f + b2[q * 4 + 0];
        o[q].y = acc[q * 4 + 1] * 256.0f + b2[q * 4 + 1];
        o[q].z = acc[q * 4 + 2] * 256.0f + b2[q * 4 + 2];
        o[q].w = acc[q * 4 + 3] * 256.0f + b2[q * 4 + 3];
    }
    float4* dst = (float4*)(outp + (size_t)d * 16);
#pragma unroll
    for (int q = 0; q < 4; ++q) dst[q] = o[q];
}

extern "C" void kernel_launch(void* const* d_in, const int* in_sizes, int n_in,
                              void* d_out, int out_size, void* d_ws, size_t ws_size,
                              hipStream_t stream) {
    const float* h   = (const float*)d_in[0];
    const float* pos = (const float*)d_in[1];
    const int*   nbr = (const int*)d_in[2];
    const float* W0  = (const float*)d_in[3];
    const float* b0  = (const float*)d_in[4];
    const float* W1  = (const float*)d_in[5];
    const float* b1  = (const float*)d_in[6];
    const float* W2  = (const float*)d_in[7];
    const float* b2  = (const float*)d_in[8];

    const int N = NNODES;

    // ws: h1 (64 MiB) + P (64 MiB) = 128 MiB exactly.
    char* w = (char*)d_ws;
    __half* h1 = (__half*)w;                               // 67,108,864 B
    __half* P  = (__half*)(w + (size_t)67108864);          // 67,108,864 B
    __half* invd2 = (__half*)w;                            // 4 MiB, into dead h1

    // d_out doubles as scratch until reduce overwrites all of it (16 MiB).
    char* ob = (char*)d_out;
    __half* invd = (__half*)(ob + 0);                      // 4,194,304 B
    __half* h16  = (__half*)(ob + 4194304);                // 8,388,608 B
    __half* W0f  = (__half*)(ob + 12582912);               // 32,768 B
    __half* W1f  = (__half*)(ob + 12615680);               // 262,144 B
    __half* Wf2s = (__half*)(ob + 12877824);               // 32,768 B (end 12,910,592)

    conv_h_kernel<<<(N * 16 + 255) / 256, 256, 0, stream>>>(h, h16, N * 16);
    prep_edges_kernel<<<(N * 8 + 255) / 256, 256, 0, stream>>>(pos, nbr, invd, N * 8);
    shuffle_w_kernel<<<(128 * 128 + 255) / 256, 256, 0, stream>>>(W0, W0f, 128, 128);
    shuffle_w_kernel<<<(1024 * 128 + 255) / 256, 256, 0, stream>>>(W1, W1f, 1024, 128);
    shuffle_w2s_kernel<<<(128 * 128 + 255) / 256, 256, 0, stream>>>(W2, Wf2s);

    layer0_kernel<<<N / 128, 256, 0, stream>>>(h16, invd, nbr, W0f, b0, h1);
    layer1p_kernel<<<N / 64, 256, 0, stream>>>(h1, invd, nbr, W1f, Wf2s, b1, P);

    // h1 is dead now; move invd out of d_out before reduce writes d_out.
    (void)hipMemcpyAsync(invd2, invd, 4194304, hipMemcpyDeviceToDevice, stream);

    reduce_kernel<<<N / 256, 256, 0, stream>>>(P, invd2, nbr, b2, (float*)d_out);
}

// Round 4
// 327.499 us; speedup vs baseline: 1.0131x; 1.0131x over previous
//
#include <hip/hip_runtime.h>
#include <hip/hip_fp16.h>

// 3-layer gather-GEMM GNN (N=262144, K=8, 16->128->128->16), f16 MFMA.
// Round 16: kill the (256,4) spill at its true source. r14/r15's scratch
// traffic came from TWO disjoint 32-reg accumulator webs (acc for the main
// GEMM, acc2 for the fused P projection): 64 arch + 64 acc = exactly the
// 128-reg cap, so transients spilled. Fix: REUSE acc for the P GEMM
// (zeroed after the h2 epilogue) — same variable = one web, −32 unified
// regs. Headroom restores r14's half-width Bn prefetch ring (+16 regs),
// which r15 proved covers the B-load L2 latency. Steady state ≈112 < 128.
// All accumulation orders unchanged -> bit-identical output.
//   * ga[2][4] reg-staged gather ring (crosses barriers, depth 2).
//   * half-width Bn ring (Bc/Bn 2x2) — restored from r14.
//   * roff4 / on-demand invd scalars / 2-slot idxQ — kept.
//   * __launch_bounds__(256, 4): 4 blocks/CU, LDS 4x32KB = 128 KB.
//
// Workspace: ws = h1 (64 MiB) + P (64 MiB) = 128 MiB exactly. invd/h16/Wf live
// in d_out scratch; invd is d2d-copied into dead h1 before the reduce (which
// writes d_out).

typedef _Float16 f16x8 __attribute__((ext_vector_type(8)));
typedef float f32x4 __attribute__((ext_vector_type(4)));

#define NNODES 262144

__global__ __launch_bounds__(256) void conv_h_kernel(const float* __restrict__ h,
                                                     __half* __restrict__ h16, int n) {
    int i = blockIdx.x * 256 + threadIdx.x;
    if (i < n) h16[i] = __float2half(h[i]);
}

__global__ __launch_bounds__(256) void prep_edges_kernel(const float* __restrict__ pos,
                                                         const int* __restrict__ nbr,
                                                         __half* __restrict__ invd, int n_edges) {
    int e = blockIdx.x * 256 + threadIdx.x;
    if (e >= n_edges) return;
    int i = e >> 3;
    int n = nbr[e];
    float dx = pos[i * 3 + 0] - pos[n * 3 + 0];
    float dy = pos[i * 3 + 1] - pos[n * 3 + 1];
    float dz = pos[i * 3 + 2] - pos[n * 3 + 2];
    float d = sqrtf(dx * dx + dy * dy + dz * dz);
    if (d == 0.0f) d = 0.5f;                       // reference: where(dist==0, 0.5, dist)
    invd[e] = __float2half((1.0f / d) * 0.00390625f);  // prescale 1/256
}

// Pre-shuffle W [KT][FO] (row-major f32) into MFMA B-fragment order:
// Wf[((s*NT + t)*64 + lane)*8 + j] = W[s*32 + (lane>>4)*8 + j][t*16 + (lane&15)]
__global__ __launch_bounds__(256) void shuffle_w_kernel(const float* __restrict__ W,
                                                        __half* __restrict__ Wf,
                                                        int KT, int FO) {
    int e = blockIdx.x * 256 + threadIdx.x;
    if (e >= KT * FO) return;
    int j = e & 7;
    int lane = (e >> 3) & 63;
    int rest = e >> 9;
    int NT = FO >> 4;
    int t = rest % NT;
    int s = rest / NT;
    int k = s * 32 + (lane >> 4) * 8 + j;
    int n = t * 16 + (lane & 15);
    Wf[e] = __float2half(W[k * FO + n]);
}

// Fragment-order for the STACKED W2: W2s[k][t*16+c] = W2[t*128+k][c]
// (W2 row-major [1024][16]; KT=128, FO=128 -> NT=8).
__global__ __launch_bounds__(256) void shuffle_w2s_kernel(const float* __restrict__ W2,
                                                          __half* __restrict__ Wf) {
    int e = blockIdx.x * 256 + threadIdx.x;
    if (e >= 128 * 128) return;
    int j = e & 7;
    int lane = (e >> 3) & 63;
    int rest = e >> 9;
    int t = rest % 8;
    int s = rest / 8;
    int k = s * 32 + (lane >> 4) * 8 + j;
    Wf[e] = __float2half(W2[(size_t)(t * 128 + k) * 16 + (lane & 15)]);
}

// ---------------- L0: F_IN=16, F_OUT=128, 128 rows/block ----------------
__global__ __launch_bounds__(256) void layer0_kernel(
    const __half* __restrict__ hprev, const __half* __restrict__ invd,
    const int* __restrict__ nbr, const __half* __restrict__ Wf,
    const float* __restrict__ bias, __half* __restrict__ outp) {
    __shared__ __align__(16) __half Bs[16384];  // 32 KB weights, staged once

    const int tid = threadIdx.x;
    const int wave = tid >> 6;
    const int lane = tid & 63;
    const int quad = lane >> 4;
    const int lmod = lane & 15;
    const int mbase = blockIdx.x * 128 + wave * 16 + lmod;

    int idx[2][8];
    f16x8 invr[2];
#pragma unroll
    for (int mt = 0; mt < 2; ++mt) {
        const int m = mbase + mt * 64;
        const int4* nrow = (const int4*)(nbr + (size_t)m * 8);
        const int4 iA = nrow[0];
        const int4 iB = nrow[1];
        idx[mt][0] = iA.x; idx[mt][1] = iA.y; idx[mt][2] = iA.z; idx[mt][3] = iA.w;
        idx[mt][4] = iB.x; idx[mt][5] = iB.y; idx[mt][6] = iB.z; idx[mt][7] = iB.w;
        invr[mt] = *(const f16x8*)(invd + (size_t)m * 8);
    }

    f32x4 acc[2][8];
#pragma unroll
    for (int mt = 0; mt < 2; ++mt)
#pragma unroll
        for (int t = 0; t < 8; ++t) acc[mt][t] = f32x4{0.f, 0.f, 0.f, 0.f};

    {
        const uint4* src = (const uint4*)Wf;
        uint4* dst = (uint4*)Bs;
#pragma unroll
        for (int i = 0; i < 8; ++i) dst[i * 256 + tid] = src[i * 256 + tid];
    }
    __syncthreads();

#pragma unroll
    for (int s = 0; s < 4; ++s) {
        const int nb = 2 * s + (quad >> 1);
        f16x8 as[2];
#pragma unroll
        for (int mt = 0; mt < 2; ++mt) {
            f16x8 av = *(const f16x8*)(hprev + (size_t)idx[mt][nb] * 16 + (quad & 1) * 8);
            as[mt] = av * invr[mt][nb];
        }
#pragma unroll
        for (int t = 0; t < 8; ++t) {
            f16x8 b = *(const f16x8*)(Bs + ((size_t)(s * 8 + t) * 64 + lane) * 8);
#pragma unroll
            for (int mt = 0; mt < 2; ++mt)
                acc[mt][t] = __builtin_amdgcn_mfma_f32_16x16x32_f16(as[mt], b, acc[mt][t], 0, 0, 0);
        }
    }

#pragma unroll
    for (int mt = 0; mt < 2; ++mt) {
        const int rbase = blockIdx.x * 128 + mt * 64 + wave * 16 + quad * 4;
#pragma unroll
        for (int t = 0; t < 8; ++t) {
            const int col = t * 16 + lmod;
            const float bv = bias[col];
#pragma unroll
            for (int rr = 0; rr < 4; ++rr) {
                float v = acc[mt][t][rr] * 256.0f + bv;
                outp[(size_t)(rbase + rr) * 128 + col] = __float2half(v);
            }
        }
    }
}

// ------- L1+P: F_IN=128, F_OUT=128, 64 rows/block, fused P projection -------
// LDS: seg-major + XOR swizzle, 16B granules: off16(seg,row) =
//   seg*64 + (row & ~15) + ((row ^ seg) & 15)   -> spans [0, 1024) granules.
__device__ __forceinline__ int off16(int seg, int row) {
    return seg * 64 + (row & ~15) + ((row ^ seg) & 15);
}

__global__ __launch_bounds__(256, 4) void layer1p_kernel(
    const __half* __restrict__ hprev, const __half* __restrict__ invd,
    const int* __restrict__ nbr, const __half* __restrict__ Wf,
    const __half* __restrict__ Wf2s, const float* __restrict__ bias,
    __half* __restrict__ Pout) {
    __shared__ __align__(16) __half As[2][8192];  // 2 x 1024 granules x 16B = 32 KB

    const int tid = threadIdx.x;
    const int wave = tid >> 6;
    const int lane = tid & 63;
    const int quad = lane >> 4;
    const int lmod = lane & 15;
    const int rowblk = blockIdx.x * 64;
    const int seg = lmod;  // staging: this thread's 16B segment

    // Thread's 4 staged rows: srow(i) = wave*16 + i*4 + quad; global row
    // rbase + i*4 with rbase = rowblk + wave*16 + quad.  nbr/invd rows for
    // (i, nb) sit at base + i*32 + nb -> one base pointer, imm offsets.
    const int rbase = rowblk + wave * 16 + quad;
    const int* nbp = nbr + (size_t)rbase * 8;
    const __half* ivp = invd + (size_t)rbase * 8;

    int soff[4];
#pragma unroll
    for (int i = 0; i < 4; ++i) {
        const int srow = wave * 16 + i * 4 + quad;
        soff[i] = off16(seg, srow) * 8;  // halves
    }

    // Fragment-read offsets (halves): off16(ks*4+quad, m*16+lmod)*8 =
    // roff4[ks] + m*128.
    int roff4[4];
#pragma unroll
    for (int ks = 0; ks < 4; ++ks) {
        const int sg = ks * 4 + quad;
        roff4[ks] = (sg * 64 + ((lmod ^ sg) & 15)) * 8;
    }

    // This wave's two output col-tiles: t = wave*2 + tl.
    const __half* WfB = Wf + ((size_t)(wave * 2) * 64 + lane) * 8;

    // Half-width B ring: phase p = nb*2 + h covers s = 2p, 2p+1.
    f16x8 Bc[2][2], Bn[2][2];
#pragma unroll
    for (int ks2 = 0; ks2 < 2; ++ks2)
#pragma unroll
        for (int tl = 0; tl < 2; ++tl)
            Bc[ks2][tl] = *(const f16x8*)(WfB + (size_t)(ks2 * 8 + tl) * 512);

    // 2-deep gather ring (global->VGPR loads cross barriers) + 2-slot idx ring.
    int idxQ[2][4];
    f16x8 ga[2][4];
    {
        int id0[4], id1[4];
#pragma unroll
        for (int i = 0; i < 4; ++i) id0[i] = nbp[i * 32 + 0];
#pragma unroll
        for (int i = 0; i < 4; ++i)
            ga[0][i] = *(const f16x8*)(hprev + (size_t)id0[i] * 128 + seg * 8);
#pragma unroll
        for (int i = 0; i < 4; ++i) id1[i] = nbp[i * 32 + 1];
#pragma unroll
        for (int i = 0; i < 4; ++i)
            ga[1][i] = *(const f16x8*)(hprev + (size_t)id1[i] * 128 + seg * 8);
#pragma unroll
        for (int i = 0; i < 4; ++i) idxQ[0][i] = nbp[i * 32 + 2];
#pragma unroll
        for (int i = 0; i < 4; ++i) idxQ[1][i] = nbp[i * 32 + 3];
    }

    // Stage neighbor 0 (scaled) into As[0].
#pragma unroll
    for (int i = 0; i < 4; ++i) {
        const _Float16 sc = *(const _Float16*)(ivp + i * 32 + 0);
        f16x8 v = ga[0][i] * sc;
        *(f16x8*)(&As[0][soff[i]]) = v;
    }
    __syncthreads();

    f32x4 acc[4][2];
#pragma unroll
    for (int m = 0; m < 4; ++m) { acc[m][0] = f32x4{0.f,0.f,0.f,0.f}; acc[m][1] = f32x4{0.f,0.f,0.f,0.f}; }

#pragma unroll
    for (int nb = 0; nb < 8; ++nb) {
        const int cur = nb & 1;
        // Issue gathers for neighbor nb+2 into ga[cur] (slot's old data =
        // neighbor nb, staged at end of iter nb-1).  Crosses barriers freely.
        if (nb < 6) {
#pragma unroll
            for (int i = 0; i < 4; ++i)
                ga[cur][i] = *(const f16x8*)(hprev + (size_t)idxQ[cur][i] * 128 + seg * 8);
        }
        // Refill idx ring: neighbor nb+4 into the slot just consumed.
        if (nb < 4) {
#pragma unroll
            for (int i = 0; i < 4; ++i)
                idxQ[cur][i] = nbp[i * 32 + nb + 4];
        }
        // Compute from As[cur]: two B half-phases (ks = h*2 + ks2).
#pragma unroll
        for (int h = 0; h < 2; ++h) {
            const int p = nb * 2 + h;
            if (p < 15) {
#pragma unroll
                for (int ks2 = 0; ks2 < 2; ++ks2)
#pragma unroll
                    for (int tl = 0; tl < 2; ++tl)
                        Bn[ks2][tl] = *(const f16x8*)(WfB + (size_t)(((p + 1) * 2 + ks2) * 8 + tl) * 512);
            }
#pragma unroll
            for (int m = 0; m < 4; ++m) {
#pragma unroll
                for (int ks2 = 0; ks2 < 2; ++ks2) {
                    f16x8 a = *(const f16x8*)(&As[cur][roff4[h * 2 + ks2] + m * 128]);
                    acc[m][0] = __builtin_amdgcn_mfma_f32_16x16x32_f16(a, Bc[ks2][0], acc[m][0], 0, 0, 0);
                    acc[m][1] = __builtin_amdgcn_mfma_f32_16x16x32_f16(a, Bc[ks2][1], acc[m][1], 0, 0, 0);
                }
            }
#pragma unroll
            for (int ks2 = 0; ks2 < 2; ++ks2) {
                Bc[ks2][0] = Bn[ks2][0];
                Bc[ks2][1] = Bn[ks2][1];
            }
        }
        // Stage neighbor nb+1 (scaled) into As[cur^1], then barrier.
        if (nb < 7) {
#pragma unroll
            for (int i = 0; i < 4; ++i) {
                const _Float16 sc = *(const _Float16*)(ivp + i * 32 + nb + 1);
                f16x8 v = ga[(nb + 1) & 1][i] * sc;
                *(f16x8*)(&As[cur ^ 1][soff[i]]) = v;
            }
            __syncthreads();
        }
    }

    // ---- Fused epilogue: h2 = leaky(acc*256 + b1) -> LDS (swizzled) ----
    // As[0] is free: its last reader was nb=6's compute, before the last
    // barrier. h2 tile = 64 rows x 128 cols, element (row,col) at granule
    // off16(col>>3, row), half (col&7).
    __half* As0 = &As[0][0];
#pragma unroll
    for (int m = 0; m < 4; ++m) {
#pragma unroll
        for (int tl = 0; tl < 2; ++tl) {
            const int col = wave * 32 + tl * 16 + lmod;
            const float bv = bias[col];
            const int sg = col >> 3;
            const int jj = col & 7;
#pragma unroll
            for (int rr = 0; rr < 4; ++rr) {
                const int row = m * 16 + quad * 4 + rr;
                float v = acc[m][tl][rr] * 256.0f + bv;
                v = (v >= 0.f) ? v : 0.01f * v;
                As0[off16(sg, row) * 8 + jj] = __float2half(v);
            }
        }
    }
    __syncthreads();

    // ---- P = h2 @ W2s (K=128, 4 k-steps); wave owns col-tiles wave*2+tl ----
    // REUSE acc (one accumulator web; the r14/r15 spill was acc+acc2 = 64
    // unified regs pinning the cap).
    const __half* WfB2 = Wf2s + ((size_t)(wave * 2) * 64 + lane) * 8;
    f16x8 B2[4][2];
#pragma unroll
    for (int ks = 0; ks < 4; ++ks)
#pragma unroll
        for (int tl = 0; tl < 2; ++tl)
            B2[ks][tl] = *(const f16x8*)(WfB2 + (size_t)(ks * 8 + tl) * 512);

#pragma unroll
    for (int m = 0; m < 4; ++m) { acc[m][0] = f32x4{0.f,0.f,0.f,0.f}; acc[m][1] = f32x4{0.f,0.f,0.f,0.f}; }
#pragma unroll
    for (int m = 0; m < 4; ++m) {
#pragma unroll
        for (int ks = 0; ks < 4; ++ks) {
            f16x8 a2 = *(const f16x8*)(&As0[roff4[ks] + m * 128]);
            acc[m][0] = __builtin_amdgcn_mfma_f32_16x16x32_f16(a2, B2[ks][0], acc[m][0], 0, 0, 0);
            acc[m][1] = __builtin_amdgcn_mfma_f32_16x16x32_f16(a2, B2[ks][1], acc[m][1], 0, 0, 0);
        }
    }

    // ---- write P (fp16, true scale) ----
#pragma unroll
    for (int m = 0; m < 4; ++m) {
#pragma unroll
        for (int tl = 0; tl < 2; ++tl) {
            const int col = wave * 32 + tl * 16 + lmod;
#pragma unroll
            for (int rr = 0; rr < 4; ++rr) {
                const int grow = rowblk + m * 16 + quad * 4 + rr;
                Pout[(size_t)grow * 128 + col] = __float2half(acc[m][tl][rr]);
            }
        }
    }
}

// ---------------- Reduce: out[i] = 256*sum_k invd[i,k]*P[nbr[i,k]][k*16..]+b2
__global__ __launch_bounds__(256) void reduce_kernel(
    const __half* __restrict__ P, const __half* __restrict__ invd,
    const int* __restrict__ nbr, const float* __restrict__ b2,
    float* __restrict__ outp) {
    const int d = blockIdx.x * 256 + threadIdx.x;

    const int4* nrow = (const int4*)(nbr + (size_t)d * 8);
    const int4 iA = nrow[0];
    const int4 iB = nrow[1];
    const int idx[8] = {iA.x, iA.y, iA.z, iA.w, iB.x, iB.y, iB.z, iB.w};
    const f16x8 iv = *(const f16x8*)(invd + (size_t)d * 8);

    // Issue all 16 gather loads up front.
    f16x8 lo[8], hi[8];
#pragma unroll
    for (int k = 0; k < 8; ++k) {
        const __half* p = P + (size_t)idx[k] * 128 + k * 16;
        lo[k] = *(const f16x8*)p;
        hi[k] = *(const f16x8*)(p + 8);
    }

    float acc[16];
#pragma unroll
    for (int c = 0; c < 16; ++c) acc[c] = 0.f;
#pragma unroll
    for (int k = 0; k < 8; ++k) {
        const float w = (float)iv[k];
#pragma unroll
        for (int c = 0; c < 8; ++c) {
            acc[c] += w * (float)lo[k][c];
            acc[c + 8] += w * (float)hi[k][c];
        }
    }

    float4 o[4];
#pragma unroll
    for (int q = 0; q < 4; ++q) {
        o[q].x = acc[q * 4 + 0] * 256.0f + b2[q * 4 + 0];
        o[q].y = acc[q * 4 + 1] * 256.0f + b2[q * 4 + 1];
        o[q].z = acc[q * 4 + 2] * 256.0f + b2[q * 4 + 2];
        o[q].w = acc[q * 4 + 3] * 256.0f + b2[q * 4 + 3];
    }
    float4* dst = (float4*)(outp + (size_t)d * 16);
#pragma unroll
    for (int q = 0; q < 4; ++q) dst[q] = o[q];
}

extern "C" void kernel_launch(void* const* d_in, const int* in_sizes, int n_in,
                              void* d_out, int out_size, void* d_ws, size_t ws_size,
                              hipStream_t stream) {
    const float* h   = (const float*)d_in[0];
    const float* pos = (const float*)d_in[1];
    const int*   nbr = (const int*)d_in[2];
    const float* W0  = (const float*)d_in[3];
    const float* b0  = (const float*)d_in[4];
    const float* W1  = (const float*)d_in[5];
    const float* b1  = (const float*)d_in[6];
    const float* W2  = (const float*)d_in[7];
    const float* b2  = (const float*)d_in[8];

    const int N = NNODES;

    // ws: h1 (64 MiB) + P (64 MiB) = 128 MiB exactly.
    char* w = (char*)d_ws;
    __half* h1 = (__half*)w;                               // 67,108,864 B
    __half* P  = (__half*)(w + (size_t)67108864);          // 67,108,864 B
    __half* invd2 = (__half*)w;                            // 4 MiB, into dead h1

    // d_out doubles as scratch until reduce overwrites all of it (16 MiB).
    char* ob = (char*)d_out;
    __half* invd = (__half*)(ob + 0);                      // 4,194,304 B
    __half* h16  = (__half*)(ob + 4194304);                // 8,388,608 B
    __half* W0f  = (__half*)(ob + 12582912);               // 32,768 B
    __half* W1f  = (__half*)(ob + 12615680);               // 262,144 B
    __half* Wf2s = (__half*)(ob + 12877824);               // 32,768 B (end 12,910,592)

    conv_h_kernel<<<(N * 16 + 255) / 256, 256, 0, stream>>>(h, h16, N * 16);
    prep_edges_kernel<<<(N * 8 + 255) / 256, 256, 0, stream>>>(pos, nbr, invd, N * 8);
    shuffle_w_kernel<<<(128 * 128 + 255) / 256, 256, 0, stream>>>(W0, W0f, 128, 128);
    shuffle_w_kernel<<<(1024 * 128 + 255) / 256, 256, 0, stream>>>(W1, W1f, 1024, 128);
    shuffle_w2s_kernel<<<(128 * 128 + 255) / 256, 256, 0, stream>>>(W2, Wf2s);

    layer0_kernel<<<N / 128, 256, 0, stream>>>(h16, invd, nbr, W0f, b0, h1);
    layer1p_kernel<<<N / 64, 256, 0, stream>>>(h1, invd, nbr, W1f, Wf2s, b1, P);

    // h1 is dead now; move invd out of d_out before reduce writes d_out.
    (void)hipMemcpyAsync(invd2, invd, 4194304, hipMemcpyDeviceToDevice, stream);

    reduce_kernel<<<N / 256, 256, 0, stream>>>(P, invd2, nbr, b2, (float*)d_out);
}

// Round 5
// 318.190 us; speedup vs baseline: 1.0427x; 1.0293x over previous
//
#include <hip/hip_runtime.h>
#include <hip/hip_fp16.h>

// 3-layer gather-GEMM GNN (N=262144, K=8, 16->128->128->16), f16 MFMA.
// Round 17: layer1p is at its structural optimum (~117us; r14/r15/r16 showed
// reg-cap spill vs latency trade is balanced). This round attacks the OTHER
// ~210us of the pipeline:
//   * reduce_kernel: was grid-capped at 1024 blocks = 16 waves/CU with 16
//     random 16B gathers/thread -> latency-bound. Split each node's 16 cols
//     across 2 threads (8 gathers/thread, 2048 blocks, 32 waves/CU): same
//     bytes, 2x memory concurrency. Per-element accumulation order unchanged
//     -> bit-identical.
//   * layer0 epilogue: 64x 2B scalar global stores/thread -> bounce the
//     128x128 f16 tile through the dead Bs LDS buffer (exactly 32KB), dump
//     with 8x 16B coalesced stores/thread. Same values -> bit-identical.
//   * layer1p: unchanged from r16 (control: expect same counters).
//
// Workspace: ws = h1 (64 MiB) + P (64 MiB) = 128 MiB exactly. invd/h16/Wf live
// in d_out scratch; invd is d2d-copied into dead h1 before the reduce (which
// writes d_out).

typedef _Float16 f16x8 __attribute__((ext_vector_type(8)));
typedef float f32x4 __attribute__((ext_vector_type(4)));

#define NNODES 262144

__global__ __launch_bounds__(256) void conv_h_kernel(const float* __restrict__ h,
                                                     __half* __restrict__ h16, int n) {
    int i = blockIdx.x * 256 + threadIdx.x;
    if (i < n) h16[i] = __float2half(h[i]);
}

__global__ __launch_bounds__(256) void prep_edges_kernel(const float* __restrict__ pos,
                                                         const int* __restrict__ nbr,
                                                         __half* __restrict__ invd, int n_edges) {
    int e = blockIdx.x * 256 + threadIdx.x;
    if (e >= n_edges) return;
    int i = e >> 3;
    int n = nbr[e];
    float dx = pos[i * 3 + 0] - pos[n * 3 + 0];
    float dy = pos[i * 3 + 1] - pos[n * 3 + 1];
    float dz = pos[i * 3 + 2] - pos[n * 3 + 2];
    float d = sqrtf(dx * dx + dy * dy + dz * dz);
    if (d == 0.0f) d = 0.5f;                       // reference: where(dist==0, 0.5, dist)
    invd[e] = __float2half((1.0f / d) * 0.00390625f);  // prescale 1/256
}

// Pre-shuffle W [KT][FO] (row-major f32) into MFMA B-fragment order:
// Wf[((s*NT + t)*64 + lane)*8 + j] = W[s*32 + (lane>>4)*8 + j][t*16 + (lane&15)]
__global__ __launch_bounds__(256) void shuffle_w_kernel(const float* __restrict__ W,
                                                        __half* __restrict__ Wf,
                                                        int KT, int FO) {
    int e = blockIdx.x * 256 + threadIdx.x;
    if (e >= KT * FO) return;
    int j = e & 7;
    int lane = (e >> 3) & 63;
    int rest = e >> 9;
    int NT = FO >> 4;
    int t = rest % NT;
    int s = rest / NT;
    int k = s * 32 + (lane >> 4) * 8 + j;
    int n = t * 16 + (lane & 15);
    Wf[e] = __float2half(W[k * FO + n]);
}

// Fragment-order for the STACKED W2: W2s[k][t*16+c] = W2[t*128+k][c]
// (W2 row-major [1024][16]; KT=128, FO=128 -> NT=8).
__global__ __launch_bounds__(256) void shuffle_w2s_kernel(const float* __restrict__ W2,
                                                          __half* __restrict__ Wf) {
    int e = blockIdx.x * 256 + threadIdx.x;
    if (e >= 128 * 128) return;
    int j = e & 7;
    int lane = (e >> 3) & 63;
    int rest = e >> 9;
    int t = rest % 8;
    int s = rest / 8;
    int k = s * 32 + (lane >> 4) * 8 + j;
    Wf[e] = __float2half(W2[(size_t)(t * 128 + k) * 16 + (lane & 15)]);
}

// ---------------- L0: F_IN=16, F_OUT=128, 128 rows/block ----------------
__global__ __launch_bounds__(256) void layer0_kernel(
    const __half* __restrict__ hprev, const __half* __restrict__ invd,
    const int* __restrict__ nbr, const __half* __restrict__ Wf,
    const float* __restrict__ bias, __half* __restrict__ outp) {
    __shared__ __align__(16) __half Bs[16384];  // 32 KB: weights, then h1-tile bounce

    const int tid = threadIdx.x;
    const int wave = tid >> 6;
    const int lane = tid & 63;
    const int quad = lane >> 4;
    const int lmod = lane & 15;
    const int mbase = blockIdx.x * 128 + wave * 16 + lmod;

    int idx[2][8];
    f16x8 invr[2];
#pragma unroll
    for (int mt = 0; mt < 2; ++mt) {
        const int m = mbase + mt * 64;
        const int4* nrow = (const int4*)(nbr + (size_t)m * 8);
        const int4 iA = nrow[0];
        const int4 iB = nrow[1];
        idx[mt][0] = iA.x; idx[mt][1] = iA.y; idx[mt][2] = iA.z; idx[mt][3] = iA.w;
        idx[mt][4] = iB.x; idx[mt][5] = iB.y; idx[mt][6] = iB.z; idx[mt][7] = iB.w;
        invr[mt] = *(const f16x8*)(invd + (size_t)m * 8);
    }

    f32x4 acc[2][8];
#pragma unroll
    for (int mt = 0; mt < 2; ++mt)
#pragma unroll
        for (int t = 0; t < 8; ++t) acc[mt][t] = f32x4{0.f, 0.f, 0.f, 0.f};

    {
        const uint4* src = (const uint4*)Wf;
        uint4* dst = (uint4*)Bs;
#pragma unroll
        for (int i = 0; i < 8; ++i) dst[i * 256 + tid] = src[i * 256 + tid];
    }
    __syncthreads();

#pragma unroll
    for (int s = 0; s < 4; ++s) {
        const int nb = 2 * s + (quad >> 1);
        f16x8 as[2];
#pragma unroll
        for (int mt = 0; mt < 2; ++mt) {
            f16x8 av = *(const f16x8*)(hprev + (size_t)idx[mt][nb] * 16 + (quad & 1) * 8);
            as[mt] = av * invr[mt][nb];
        }
#pragma unroll
        for (int t = 0; t < 8; ++t) {
            f16x8 b = *(const f16x8*)(Bs + ((size_t)(s * 8 + t) * 64 + lane) * 8);
#pragma unroll
            for (int mt = 0; mt < 2; ++mt)
                acc[mt][t] = __builtin_amdgcn_mfma_f32_16x16x32_f16(as[mt], b, acc[mt][t], 0, 0, 0);
        }
    }

    // ---- Epilogue: bounce 128x128 f16 tile through Bs, coalesced dump ----
    __syncthreads();  // all Bs (weights) reads complete before overwrite
#pragma unroll
    for (int mt = 0; mt < 2; ++mt) {
#pragma unroll
        for (int t = 0; t < 8; ++t) {
            const int col = t * 16 + lmod;
            const float bv = bias[col];
#pragma unroll
            for (int rr = 0; rr < 4; ++rr) {
                const int lrow = mt * 64 + wave * 16 + quad * 4 + rr;
                float v = acc[mt][t][rr] * 256.0f + bv;
                Bs[lrow * 128 + col] = __float2half(v);
            }
        }
    }
    __syncthreads();
    {
        const int lrow = tid >> 1;                 // 0..127
        const int cb = (tid & 1) * 64;             // col base 0 or 64
        __half* gdst = outp + (size_t)(blockIdx.x * 128 + lrow) * 128 + cb;
        const __half* lsrc = Bs + lrow * 128 + cb;
#pragma unroll
        for (int j = 0; j < 8; ++j)
            *(f16x8*)(gdst + j * 8) = *(const f16x8*)(lsrc + j * 8);
    }
}

// ------- L1+P: F_IN=128, F_OUT=128, 64 rows/block, fused P projection -------
// LDS: seg-major + XOR swizzle, 16B granules: off16(seg,row) =
//   seg*64 + (row & ~15) + ((row ^ seg) & 15)   -> spans [0, 1024) granules.
__device__ __forceinline__ int off16(int seg, int row) {
    return seg * 64 + (row & ~15) + ((row ^ seg) & 15);
}

__global__ __launch_bounds__(256, 4) void layer1p_kernel(
    const __half* __restrict__ hprev, const __half* __restrict__ invd,
    const int* __restrict__ nbr, const __half* __restrict__ Wf,
    const __half* __restrict__ Wf2s, const float* __restrict__ bias,
    __half* __restrict__ Pout) {
    __shared__ __align__(16) __half As[2][8192];  // 2 x 1024 granules x 16B = 32 KB

    const int tid = threadIdx.x;
    const int wave = tid >> 6;
    const int lane = tid & 63;
    const int quad = lane >> 4;
    const int lmod = lane & 15;
    const int rowblk = blockIdx.x * 64;
    const int seg = lmod;  // staging: this thread's 16B segment

    // Thread's 4 staged rows: srow(i) = wave*16 + i*4 + quad; global row
    // rbase + i*4 with rbase = rowblk + wave*16 + quad.  nbr/invd rows for
    // (i, nb) sit at base + i*32 + nb -> one base pointer, imm offsets.
    const int rbase = rowblk + wave * 16 + quad;
    const int* nbp = nbr + (size_t)rbase * 8;
    const __half* ivp = invd + (size_t)rbase * 8;

    int soff[4];
#pragma unroll
    for (int i = 0; i < 4; ++i) {
        const int srow = wave * 16 + i * 4 + quad;
        soff[i] = off16(seg, srow) * 8;  // halves
    }

    // Fragment-read offsets (halves): off16(ks*4+quad, m*16+lmod)*8 =
    // roff4[ks] + m*128.
    int roff4[4];
#pragma unroll
    for (int ks = 0; ks < 4; ++ks) {
        const int sg = ks * 4 + quad;
        roff4[ks] = (sg * 64 + ((lmod ^ sg) & 15)) * 8;
    }

    // This wave's two output col-tiles: t = wave*2 + tl.
    const __half* WfB = Wf + ((size_t)(wave * 2) * 64 + lane) * 8;

    // Half-width B ring: phase p = nb*2 + h covers s = 2p, 2p+1.
    f16x8 Bc[2][2], Bn[2][2];
#pragma unroll
    for (int ks2 = 0; ks2 < 2; ++ks2)
#pragma unroll
        for (int tl = 0; tl < 2; ++tl)
            Bc[ks2][tl] = *(const f16x8*)(WfB + (size_t)(ks2 * 8 + tl) * 512);

    // 2-deep gather ring (global->VGPR loads cross barriers) + 2-slot idx ring.
    int idxQ[2][4];
    f16x8 ga[2][4];
    {
        int id0[4], id1[4];
#pragma unroll
        for (int i = 0; i < 4; ++i) id0[i] = nbp[i * 32 + 0];
#pragma unroll
        for (int i = 0; i < 4; ++i)
            ga[0][i] = *(const f16x8*)(hprev + (size_t)id0[i] * 128 + seg * 8);
#pragma unroll
        for (int i = 0; i < 4; ++i) id1[i] = nbp[i * 32 + 1];
#pragma unroll
        for (int i = 0; i < 4; ++i)
            ga[1][i] = *(const f16x8*)(hprev + (size_t)id1[i] * 128 + seg * 8);
#pragma unroll
        for (int i = 0; i < 4; ++i) idxQ[0][i] = nbp[i * 32 + 2];
#pragma unroll
        for (int i = 0; i < 4; ++i) idxQ[1][i] = nbp[i * 32 + 3];
    }

    // Stage neighbor 0 (scaled) into As[0].
#pragma unroll
    for (int i = 0; i < 4; ++i) {
        const _Float16 sc = *(const _Float16*)(ivp + i * 32 + 0);
        f16x8 v = ga[0][i] * sc;
        *(f16x8*)(&As[0][soff[i]]) = v;
    }
    __syncthreads();

    f32x4 acc[4][2];
#pragma unroll
    for (int m = 0; m < 4; ++m) { acc[m][0] = f32x4{0.f,0.f,0.f,0.f}; acc[m][1] = f32x4{0.f,0.f,0.f,0.f}; }

#pragma unroll
    for (int nb = 0; nb < 8; ++nb) {
        const int cur = nb & 1;
        // Issue gathers for neighbor nb+2 into ga[cur] (slot's old data =
        // neighbor nb, staged at end of iter nb-1).  Crosses barriers freely.
        if (nb < 6) {
#pragma unroll
            for (int i = 0; i < 4; ++i)
                ga[cur][i] = *(const f16x8*)(hprev + (size_t)idxQ[cur][i] * 128 + seg * 8);
        }
        // Refill idx ring: neighbor nb+4 into the slot just consumed.
        if (nb < 4) {
#pragma unroll
            for (int i = 0; i < 4; ++i)
                idxQ[cur][i] = nbp[i * 32 + nb + 4];
        }
        // Compute from As[cur]: two B half-phases (ks = h*2 + ks2).
#pragma unroll
        for (int h = 0; h < 2; ++h) {
            const int p = nb * 2 + h;
            if (p < 15) {
#pragma unroll
                for (int ks2 = 0; ks2 < 2; ++ks2)
#pragma unroll
                    for (int tl = 0; tl < 2; ++tl)
                        Bn[ks2][tl] = *(const f16x8*)(WfB + (size_t)(((p + 1) * 2 + ks2) * 8 + tl) * 512);
            }
#pragma unroll
            for (int m = 0; m < 4; ++m) {
#pragma unroll
                for (int ks2 = 0; ks2 < 2; ++ks2) {
                    f16x8 a = *(const f16x8*)(&As[cur][roff4[h * 2 + ks2] + m * 128]);
                    acc[m][0] = __builtin_amdgcn_mfma_f32_16x16x32_f16(a, Bc[ks2][0], acc[m][0], 0, 0, 0);
                    acc[m][1] = __builtin_amdgcn_mfma_f32_16x16x32_f16(a, Bc[ks2][1], acc[m][1], 0, 0, 0);
                }
            }
#pragma unroll
            for (int ks2 = 0; ks2 < 2; ++ks2) {
                Bc[ks2][0] = Bn[ks2][0];
                Bc[ks2][1] = Bn[ks2][1];
            }
        }
        // Stage neighbor nb+1 (scaled) into As[cur^1], then barrier.
        if (nb < 7) {
#pragma unroll
            for (int i = 0; i < 4; ++i) {
                const _Float16 sc = *(const _Float16*)(ivp + i * 32 + nb + 1);
                f16x8 v = ga[(nb + 1) & 1][i] * sc;
                *(f16x8*)(&As[cur ^ 1][soff[i]]) = v;
            }
            __syncthreads();
        }
    }

    // ---- Fused epilogue: h2 = leaky(acc*256 + b1) -> LDS (swizzled) ----
    // As[0] is free: its last reader was nb=6's compute, before the last
    // barrier. h2 tile = 64 rows x 128 cols, element (row,col) at granule
    // off16(col>>3, row), half (col&7).
    __half* As0 = &As[0][0];
#pragma unroll
    for (int m = 0; m < 4; ++m) {
#pragma unroll
        for (int tl = 0; tl < 2; ++tl) {
            const int col = wave * 32 + tl * 16 + lmod;
            const float bv = bias[col];
            const int sg = col >> 3;
            const int jj = col & 7;
#pragma unroll
            for (int rr = 0; rr < 4; ++rr) {
                const int row = m * 16 + quad * 4 + rr;
                float v = acc[m][tl][rr] * 256.0f + bv;
                v = (v >= 0.f) ? v : 0.01f * v;
                As0[off16(sg, row) * 8 + jj] = __float2half(v);
            }
        }
    }
    __syncthreads();

    // ---- P = h2 @ W2s (K=128, 4 k-steps); wave owns col-tiles wave*2+tl ----
    const __half* WfB2 = Wf2s + ((size_t)(wave * 2) * 64 + lane) * 8;
    f16x8 B2[4][2];
#pragma unroll
    for (int ks = 0; ks < 4; ++ks)
#pragma unroll
        for (int tl = 0; tl < 2; ++tl)
            B2[ks][tl] = *(const f16x8*)(WfB2 + (size_t)(ks * 8 + tl) * 512);

#pragma unroll
    for (int m = 0; m < 4; ++m) { acc[m][0] = f32x4{0.f,0.f,0.f,0.f}; acc[m][1] = f32x4{0.f,0.f,0.f,0.f}; }
#pragma unroll
    for (int m = 0; m < 4; ++m) {
#pragma unroll
        for (int ks = 0; ks < 4; ++ks) {
            f16x8 a2 = *(const f16x8*)(&As0[roff4[ks] + m * 128]);
            acc[m][0] = __builtin_amdgcn_mfma_f32_16x16x32_f16(a2, B2[ks][0], acc[m][0], 0, 0, 0);
            acc[m][1] = __builtin_amdgcn_mfma_f32_16x16x32_f16(a2, B2[ks][1], acc[m][1], 0, 0, 0);
        }
    }

    // ---- write P (fp16, true scale) ----
#pragma unroll
    for (int m = 0; m < 4; ++m) {
#pragma unroll
        for (int tl = 0; tl < 2; ++tl) {
            const int col = wave * 32 + tl * 16 + lmod;
#pragma unroll
            for (int rr = 0; rr < 4; ++rr) {
                const int grow = rowblk + m * 16 + quad * 4 + rr;
                Pout[(size_t)grow * 128 + col] = __float2half(acc[m][tl][rr]);
            }
        }
    }
}

// ---- Reduce: out[i][c] = 256*sum_k invd[i,k]*P[nbr[i,k]][k*16+c] + b2[c] ----
// 2-way split per node: thread (d, half) covers cols half*8..+8.
// 8 gathers/thread, 2048 blocks = 32 waves/CU (was 16): 2x memory concurrency.
__global__ __launch_bounds__(256) void reduce_kernel(
    const __half* __restrict__ P, const __half* __restrict__ invd,
    const int* __restrict__ nbr, const float* __restrict__ b2,
    float* __restrict__ outp) {
    const int t = blockIdx.x * 256 + threadIdx.x;
    const int d = t >> 1;
    const int half = t & 1;

    const int4* nrow = (const int4*)(nbr + (size_t)d * 8);
    const int4 iA = nrow[0];
    const int4 iB = nrow[1];
    const int idx[8] = {iA.x, iA.y, iA.z, iA.w, iB.x, iB.y, iB.z, iB.w};
    const f16x8 iv = *(const f16x8*)(invd + (size_t)d * 8);

    // Issue all 8 gather loads up front.
    f16x8 v[8];
#pragma unroll
    for (int k = 0; k < 8; ++k)
        v[k] = *(const f16x8*)(P + (size_t)idx[k] * 128 + k * 16 + half * 8);

    float acc[8];
#pragma unroll
    for (int c = 0; c < 8; ++c) acc[c] = 0.f;
#pragma unroll
    for (int k = 0; k < 8; ++k) {
        const float w = (float)iv[k];
#pragma unroll
        for (int c = 0; c < 8; ++c) acc[c] += w * (float)v[k][c];
    }

    const float* bp = b2 + half * 8;
    float4 o[2];
#pragma unroll
    for (int q = 0; q < 2; ++q) {
        o[q].x = acc[q * 4 + 0] * 256.0f + bp[q * 4 + 0];
        o[q].y = acc[q * 4 + 1] * 256.0f + bp[q * 4 + 1];
        o[q].z = acc[q * 4 + 2] * 256.0f + bp[q * 4 + 2];
        o[q].w = acc[q * 4 + 3] * 256.0f + bp[q * 4 + 3];
    }
    float4* dst = (float4*)(outp + (size_t)d * 16 + half * 8);
    dst[0] = o[0];
    dst[1] = o[1];
}

extern "C" void kernel_launch(void* const* d_in, const int* in_sizes, int n_in,
                              void* d_out, int out_size, void* d_ws, size_t ws_size,
                              hipStream_t stream) {
    const float* h   = (const float*)d_in[0];
    const float* pos = (const float*)d_in[1];
    const int*   nbr = (const int*)d_in[2];
    const float* W0  = (const float*)d_in[3];
    const float* b0  = (const float*)d_in[4];
    const float* W1  = (const float*)d_in[5];
    const float* b1  = (const float*)d_in[6];
    const float* W2  = (const float*)d_in[7];
    const float* b2  = (const float*)d_in[8];

    const int N = NNODES;

    // ws: h1 (64 MiB) + P (64 MiB) = 128 MiB exactly.
    char* w = (char*)d_ws;
    __half* h1 = (__half*)w;                               // 67,108,864 B
    __half* P  = (__half*)(w + (size_t)67108864);          // 67,108,864 B
    __half* invd2 = (__half*)w;                            // 4 MiB, into dead h1

    // d_out doubles as scratch until reduce overwrites all of it (16 MiB).
    char* ob = (char*)d_out;
    __half* invd = (__half*)(ob + 0);                      // 4,194,304 B
    __half* h16  = (__half*)(ob + 4194304);                // 8,388,608 B
    __half* W0f  = (__half*)(ob + 12582912);               // 32,768 B
    __half* W1f  = (__half*)(ob + 12615680);               // 262,144 B
    __half* Wf2s = (__half*)(ob + 12877824);               // 32,768 B (end 12,910,592)

    conv_h_kernel<<<(N * 16 + 255) / 256, 256, 0, stream>>>(h, h16, N * 16);
    prep_edges_kernel<<<(N * 8 + 255) / 256, 256, 0, stream>>>(pos, nbr, invd, N * 8);
    shuffle_w_kernel<<<(128 * 128 + 255) / 256, 256, 0, stream>>>(W0, W0f, 128, 128);
    shuffle_w_kernel<<<(1024 * 128 + 255) / 256, 256, 0, stream>>>(W1, W1f, 1024, 128);
    shuffle_w2s_kernel<<<(128 * 128 + 255) / 256, 256, 0, stream>>>(W2, Wf2s);

    layer0_kernel<<<N / 128, 256, 0, stream>>>(h16, invd, nbr, W0f, b0, h1);
    layer1p_kernel<<<N / 64, 256, 0, stream>>>(h1, invd, nbr, W1f, Wf2s, b1, P);

    // h1 is dead now; move invd out of d_out before reduce writes d_out.
    (void)hipMemcpyAsync(invd2, invd, 4194304, hipMemcpyDeviceToDevice, stream);

    reduce_kernel<<<(N * 2) / 256, 256, 0, stream>>>(P, invd2, nbr, b2, (float*)d_out);
}

// Round 6
// 312.055 us; speedup vs baseline: 1.0632x; 1.0197x over previous
//
#include <hip/hip_runtime.h>
#include <hip/hip_fp16.h>

// 3-layer gather-GEMM GNN (N=262144, K=8, 16->128->128->16), f16 MFMA.
// Round 18: two changes.
// (1) layer1p spill elimination by cutting zero-cost registers (r16 showed
//     renaming acc doesn't merge SSA webs; r15's ring-removal was confounded
//     with B-latency exposure). Cuts:
//       * idxQ ring (8 regs) -> JIT nbr loads (thread's nbr row = one 32B
//         L1-resident line; load at iter top, hidden under MFMA).
//       * soff[4] (4 regs) -> recomputed at stage time (2 VALU/store).
//     Peak live ~114-118 < 128 -> spill-free at (256,4) WITH the Bn ring.
//     All values/orders identical -> bit-identical output.
// (2) Fuse conv_h + prep_edges + 3x shuffle into one prep_all kernel
//     (branch on blockIdx range; all regions independent) -> 4 fewer
//     dispatch overheads.
// layer0 / reduce keep r17's form (LDS-bounce epilogue; 2-way split reduce).
//
// Workspace: ws = h1 (64 MiB) + P (64 MiB) = 128 MiB exactly. invd/h16/Wf live
// in d_out scratch; invd is d2d-copied into dead h1 before the reduce (which
// writes d_out).

typedef _Float16 f16x8 __attribute__((ext_vector_type(8)));
typedef float f32x4 __attribute__((ext_vector_type(4)));

#define NNODES 262144

// ---- Fused prep: [0,16384) conv_h | [16384,24576) prep_edges |
//      [24576,24640) shuffle W0 | [24640,25152) shuffle W1 |
//      [25152,25216) shuffle W2s ----
__global__ __launch_bounds__(256) void prep_all_kernel(
    const float* __restrict__ h, __half* __restrict__ h16,
    const float* __restrict__ pos, const int* __restrict__ nbr,
    __half* __restrict__ invd,
    const float* __restrict__ W0, __half* __restrict__ W0f,
    const float* __restrict__ W1, __half* __restrict__ W1f,
    const float* __restrict__ W2, __half* __restrict__ W2f) {
    const int b = blockIdx.x;
    const int t = threadIdx.x;
    if (b < 16384) {                     // conv_h: N*16 = 4,194,304 elems
        int i = b * 256 + t;
        h16[i] = __float2half(h[i]);
    } else if (b < 24576) {              // prep_edges: N*8 = 2,097,152 edges
        int e = (b - 16384) * 256 + t;
        int i = e >> 3;
        int n = nbr[e];
        float dx = pos[i * 3 + 0] - pos[n * 3 + 0];
        float dy = pos[i * 3 + 1] - pos[n * 3 + 1];
        float dz = pos[i * 3 + 2] - pos[n * 3 + 2];
        float d = sqrtf(dx * dx + dy * dy + dz * dz);
        if (d == 0.0f) d = 0.5f;         // reference: where(dist==0, 0.5, dist)
        invd[e] = __float2half((1.0f / d) * 0.00390625f);  // prescale 1/256
    } else if (b < 24640) {              // W0 fragment shuffle: KT=128, FO=128
        int e = (b - 24576) * 256 + t;   // 16384 elems
        int j = e & 7;
        int lane = (e >> 3) & 63;
        int rest = e >> 9;
        int tt = rest % 8;
        int s = rest / 8;
        int k = s * 32 + (lane >> 4) * 8 + j;
        int n = tt * 16 + (lane & 15);
        W0f[e] = __float2half(W0[k * 128 + n]);
    } else if (b < 25152) {              // W1 fragment shuffle: KT=1024, FO=128
        int e = (b - 24640) * 256 + t;   // 131072 elems
        int j = e & 7;
        int lane = (e >> 3) & 63;
        int rest = e >> 9;
        int tt = rest % 8;
        int s = rest / 8;
        int k = s * 32 + (lane >> 4) * 8 + j;
        int n = tt * 16 + (lane & 15);
        W1f[e] = __float2half(W1[k * 128 + n]);
    } else {                             // W2 stacked shuffle: 16384 elems
        int e = (b - 25152) * 256 + t;
        int j = e & 7;
        int lane = (e >> 3) & 63;
        int rest = e >> 9;
        int tt = rest % 8;
        int s = rest / 8;
        int k = s * 32 + (lane >> 4) * 8 + j;
        W2f[e] = __float2half(W2[(size_t)(tt * 128 + k) * 16 + (lane & 15)]);
    }
}

// ---------------- L0: F_IN=16, F_OUT=128, 128 rows/block ----------------
__global__ __launch_bounds__(256) void layer0_kernel(
    const __half* __restrict__ hprev, const __half* __restrict__ invd,
    const int* __restrict__ nbr, const __half* __restrict__ Wf,
    const float* __restrict__ bias, __half* __restrict__ outp) {
    __shared__ __align__(16) __half Bs[16384];  // 32 KB: weights, then h1-tile bounce

    const int tid = threadIdx.x;
    const int wave = tid >> 6;
    const int lane = tid & 63;
    const int quad = lane >> 4;
    const int lmod = lane & 15;
    const int mbase = blockIdx.x * 128 + wave * 16 + lmod;

    int idx[2][8];
    f16x8 invr[2];
#pragma unroll
    for (int mt = 0; mt < 2; ++mt) {
        const int m = mbase + mt * 64;
        const int4* nrow = (const int4*)(nbr + (size_t)m * 8);
        const int4 iA = nrow[0];
        const int4 iB = nrow[1];
        idx[mt][0] = iA.x; idx[mt][1] = iA.y; idx[mt][2] = iA.z; idx[mt][3] = iA.w;
        idx[mt][4] = iB.x; idx[mt][5] = iB.y; idx[mt][6] = iB.z; idx[mt][7] = iB.w;
        invr[mt] = *(const f16x8*)(invd + (size_t)m * 8);
    }

    f32x4 acc[2][8];
#pragma unroll
    for (int mt = 0; mt < 2; ++mt)
#pragma unroll
        for (int t = 0; t < 8; ++t) acc[mt][t] = f32x4{0.f, 0.f, 0.f, 0.f};

    {
        const uint4* src = (const uint4*)Wf;
        uint4* dst = (uint4*)Bs;
#pragma unroll
        for (int i = 0; i < 8; ++i) dst[i * 256 + tid] = src[i * 256 + tid];
    }
    __syncthreads();

#pragma unroll
    for (int s = 0; s < 4; ++s) {
        const int nb = 2 * s + (quad >> 1);
        f16x8 as[2];
#pragma unroll
        for (int mt = 0; mt < 2; ++mt) {
            f16x8 av = *(const f16x8*)(hprev + (size_t)idx[mt][nb] * 16 + (quad & 1) * 8);
            as[mt] = av * invr[mt][nb];
        }
#pragma unroll
        for (int t = 0; t < 8; ++t) {
            f16x8 b = *(const f16x8*)(Bs + ((size_t)(s * 8 + t) * 64 + lane) * 8);
#pragma unroll
            for (int mt = 0; mt < 2; ++mt)
                acc[mt][t] = __builtin_amdgcn_mfma_f32_16x16x32_f16(as[mt], b, acc[mt][t], 0, 0, 0);
        }
    }

    // ---- Epilogue: bounce 128x128 f16 tile through Bs, coalesced dump ----
    __syncthreads();  // all Bs (weights) reads complete before overwrite
#pragma unroll
    for (int mt = 0; mt < 2; ++mt) {
#pragma unroll
        for (int t = 0; t < 8; ++t) {
            const int col = t * 16 + lmod;
            const float bv = bias[col];
#pragma unroll
            for (int rr = 0; rr < 4; ++rr) {
                const int lrow = mt * 64 + wave * 16 + quad * 4 + rr;
                float v = acc[mt][t][rr] * 256.0f + bv;
                Bs[lrow * 128 + col] = __float2half(v);
            }
        }
    }
    __syncthreads();
    {
        const int lrow = tid >> 1;                 // 0..127
        const int cb = (tid & 1) * 64;             // col base 0 or 64
        __half* gdst = outp + (size_t)(blockIdx.x * 128 + lrow) * 128 + cb;
        const __half* lsrc = Bs + lrow * 128 + cb;
#pragma unroll
        for (int j = 0; j < 8; ++j)
            *(f16x8*)(gdst + j * 8) = *(const f16x8*)(lsrc + j * 8);
    }
}

// ------- L1+P: F_IN=128, F_OUT=128, 64 rows/block, fused P projection -------
// LDS: seg-major + XOR swizzle, 16B granules: off16(seg,row) =
//   seg*64 + (row & ~15) + ((row ^ seg) & 15)   -> spans [0, 1024) granules.
__device__ __forceinline__ int off16(int seg, int row) {
    return seg * 64 + (row & ~15) + ((row ^ seg) & 15);
}

__global__ __launch_bounds__(256, 4) void layer1p_kernel(
    const __half* __restrict__ hprev, const __half* __restrict__ invd,
    const int* __restrict__ nbr, const __half* __restrict__ Wf,
    const __half* __restrict__ Wf2s, const float* __restrict__ bias,
    __half* __restrict__ Pout) {
    __shared__ __align__(16) __half As[2][8192];  // 2 x 1024 granules x 16B = 32 KB

    const int tid = threadIdx.x;
    const int wave = tid >> 6;
    const int lane = tid & 63;
    const int quad = lane >> 4;
    const int lmod = lane & 15;
    const int rowblk = blockIdx.x * 64;
    const int seg = lmod;  // staging: this thread's 16B segment

    // Thread's 4 staged rows: srow(i) = wave*16 + i*4 + quad; nbr/invd rows
    // for (i, nb) sit at base + i*32 + nb -> one base pointer, imm offsets.
    // The 32B nbr row per thread is one L1-resident cache line: indices are
    // loaded just-in-time each iteration (no idxQ ring).
    const int rbase = rowblk + wave * 16 + quad;
    const int* nbp = nbr + (size_t)rbase * 8;
    const __half* ivp = invd + (size_t)rbase * 8;

    // Stage-offset base: off16(seg, wave*16 + i*4 + quad)*8 =
    //   (lmod*64 + wave*16 + (((i*4+quad) ^ lmod) & 15)) * 8  (recomputed).
    const int sbase = lmod * 64 + wave * 16;

    // Fragment-read offsets (halves): off16(ks*4+quad, m*16+lmod)*8 =
    // roff4[ks] + m*128.
    int roff4[4];
#pragma unroll
    for (int ks = 0; ks < 4; ++ks) {
        const int sg = ks * 4 + quad;
        roff4[ks] = (sg * 64 + ((lmod ^ sg) & 15)) * 8;
    }

    // This wave's two output col-tiles: t = wave*2 + tl.
    const __half* WfB = Wf + ((size_t)(wave * 2) * 64 + lane) * 8;

    // Half-width B ring: phase p = nb*2 + h covers s = 2p, 2p+1.
    f16x8 Bc[2][2], Bn[2][2];
#pragma unroll
    for (int ks2 = 0; ks2 < 2; ++ks2)
#pragma unroll
        for (int tl = 0; tl < 2; ++tl)
            Bc[ks2][tl] = *(const f16x8*)(WfB + (size_t)(ks2 * 8 + tl) * 512);

    // 2-deep gather ring (global->VGPR loads cross barriers); indices JIT.
    f16x8 ga[2][4];
    {
        int id0[4], id1[4];
#pragma unroll
        for (int i = 0; i < 4; ++i) id0[i] = nbp[i * 32 + 0];
#pragma unroll
        for (int i = 0; i < 4; ++i)
            ga[0][i] = *(const f16x8*)(hprev + (size_t)id0[i] * 128 + seg * 8);
#pragma unroll
        for (int i = 0; i < 4; ++i) id1[i] = nbp[i * 32 + 1];
#pragma unroll
        for (int i = 0; i < 4; ++i)
            ga[1][i] = *(const f16x8*)(hprev + (size_t)id1[i] * 128 + seg * 8);
    }

    // Stage neighbor 0 (scaled) into As[0].
#pragma unroll
    for (int i = 0; i < 4; ++i) {
        const _Float16 sc = *(const _Float16*)(ivp + i * 32 + 0);
        f16x8 v = ga[0][i] * sc;
        *(f16x8*)(&As[0][(sbase + (((i * 4 + quad) ^ lmod) & 15)) * 8]) = v;
    }
    __syncthreads();

    f32x4 acc[4][2];
#pragma unroll
    for (int m = 0; m < 4; ++m) { acc[m][0] = f32x4{0.f,0.f,0.f,0.f}; acc[m][1] = f32x4{0.f,0.f,0.f,0.f}; }

#pragma unroll
    for (int nb = 0; nb < 8; ++nb) {
        const int cur = nb & 1;
        // JIT indices for neighbor nb+2 (L1-hot line), then issue gathers
        // into ga[cur] (slot's old data = neighbor nb, already staged).
        if (nb < 6) {
            int idn[4];
#pragma unroll
            for (int i = 0; i < 4; ++i) idn[i] = nbp[i * 32 + nb + 2];
#pragma unroll
            for (int i = 0; i < 4; ++i)
                ga[cur][i] = *(const f16x8*)(hprev + (size_t)idn[i] * 128 + seg * 8);
        }
        // Compute from As[cur]: two B half-phases (ks = h*2 + ks2).
#pragma unroll
        for (int h = 0; h < 2; ++h) {
            const int p = nb * 2 + h;
            if (p < 15) {
#pragma unroll
                for (int ks2 = 0; ks2 < 2; ++ks2)
#pragma unroll
                    for (int tl = 0; tl < 2; ++tl)
                        Bn[ks2][tl] = *(const f16x8*)(WfB + (size_t)(((p + 1) * 2 + ks2) * 8 + tl) * 512);
            }
#pragma unroll
            for (int m = 0; m < 4; ++m) {
#pragma unroll
                for (int ks2 = 0; ks2 < 2; ++ks2) {
                    f16x8 a = *(const f16x8*)(&As[cur][roff4[h * 2 + ks2] + m * 128]);
                    acc[m][0] = __builtin_amdgcn_mfma_f32_16x16x32_f16(a, Bc[ks2][0], acc[m][0], 0, 0, 0);
                    acc[m][1] = __builtin_amdgcn_mfma_f32_16x16x32_f16(a, Bc[ks2][1], acc[m][1], 0, 0, 0);
                }
            }
#pragma unroll
            for (int ks2 = 0; ks2 < 2; ++ks2) {
                Bc[ks2][0] = Bn[ks2][0];
                Bc[ks2][1] = Bn[ks2][1];
            }
        }
        // Stage neighbor nb+1 (scaled) into As[cur^1], then barrier.
        if (nb < 7) {
#pragma unroll
            for (int i = 0; i < 4; ++i) {
                const _Float16 sc = *(const _Float16*)(ivp + i * 32 + nb + 1);
                f16x8 v = ga[(nb + 1) & 1][i] * sc;
                *(f16x8*)(&As[cur ^ 1][(sbase + (((i * 4 + quad) ^ lmod) & 15)) * 8]) = v;
            }
            __syncthreads();
        }
    }

    // ---- Fused epilogue: h2 = leaky(acc*256 + b1) -> LDS (swizzled) ----
    // As[0] is free: its last reader was nb=6's compute, before the last
    // barrier. h2 tile = 64 rows x 128 cols, element (row,col) at granule
    // off16(col>>3, row), half (col&7).
    __half* As0 = &As[0][0];
#pragma unroll
    for (int m = 0; m < 4; ++m) {
#pragma unroll
        for (int tl = 0; tl < 2; ++tl) {
            const int col = wave * 32 + tl * 16 + lmod;
            const float bv = bias[col];
            const int sg = col >> 3;
            const int jj = col & 7;
#pragma unroll
            for (int rr = 0; rr < 4; ++rr) {
                const int row = m * 16 + quad * 4 + rr;
                float v = acc[m][tl][rr] * 256.0f + bv;
                v = (v >= 0.f) ? v : 0.01f * v;
                As0[off16(sg, row) * 8 + jj] = __float2half(v);
            }
        }
    }
    __syncthreads();

    // ---- P = h2 @ W2s (K=128, 4 k-steps); wave owns col-tiles wave*2+tl ----
    const __half* WfB2 = Wf2s + ((size_t)(wave * 2) * 64 + lane) * 8;
    f16x8 B2[4][2];
#pragma unroll
    for (int ks = 0; ks < 4; ++ks)
#pragma unroll
        for (int tl = 0; tl < 2; ++tl)
            B2[ks][tl] = *(const f16x8*)(WfB2 + (size_t)(ks * 8 + tl) * 512);

    f32x4 acc2[4][2];
#pragma unroll
    for (int m = 0; m < 4; ++m) { acc2[m][0] = f32x4{0.f,0.f,0.f,0.f}; acc2[m][1] = f32x4{0.f,0.f,0.f,0.f}; }
#pragma unroll
    for (int m = 0; m < 4; ++m) {
#pragma unroll
        for (int ks = 0; ks < 4; ++ks) {
            f16x8 a2 = *(const f16x8*)(&As0[roff4[ks] + m * 128]);
            acc2[m][0] = __builtin_amdgcn_mfma_f32_16x16x32_f16(a2, B2[ks][0], acc2[m][0], 0, 0, 0);
            acc2[m][1] = __builtin_amdgcn_mfma_f32_16x16x32_f16(a2, B2[ks][1], acc2[m][1], 0, 0, 0);
        }
    }

    // ---- write P (fp16, true scale) ----
#pragma unroll
    for (int m = 0; m < 4; ++m) {
#pragma unroll
        for (int tl = 0; tl < 2; ++tl) {
            const int col = wave * 32 + tl * 16 + lmod;
#pragma unroll
            for (int rr = 0; rr < 4; ++rr) {
                const int grow = rowblk + m * 16 + quad * 4 + rr;
                Pout[(size_t)grow * 128 + col] = __float2half(acc2[m][tl][rr]);
            }
        }
    }
}

// ---- Reduce: out[i][c] = 256*sum_k invd[i,k]*P[nbr[i,k]][k*16+c] + b2[c] ----
// 2-way split per node: thread (d, half) covers cols half*8..+8.
// 8 gathers/thread, 2048 blocks = 32 waves/CU: 2x memory concurrency.
__global__ __launch_bounds__(256) void reduce_kernel(
    const __half* __restrict__ P, const __half* __restrict__ invd,
    const int* __restrict__ nbr, const float* __restrict__ b2,
    float* __restrict__ outp) {
    const int t = blockIdx.x * 256 + threadIdx.x;
    const int d = t >> 1;
    const int half = t & 1;

    const int4* nrow = (const int4*)(nbr + (size_t)d * 8);
    const int4 iA = nrow[0];
    const int4 iB = nrow[1];
    const int idx[8] = {iA.x, iA.y, iA.z, iA.w, iB.x, iB.y, iB.z, iB.w};
    const f16x8 iv = *(const f16x8*)(invd + (size_t)d * 8);

    // Issue all 8 gather loads up front.
    f16x8 v[8];
#pragma unroll
    for (int k = 0; k < 8; ++k)
        v[k] = *(const f16x8*)(P + (size_t)idx[k] * 128 + k * 16 + half * 8);

    float acc[8];
#pragma unroll
    for (int c = 0; c < 8; ++c) acc[c] = 0.f;
#pragma unroll
    for (int k = 0; k < 8; ++k) {
        const float w = (float)iv[k];
#pragma unroll
        for (int c = 0; c < 8; ++c) acc[c] += w * (float)v[k][c];
    }

    const float* bp = b2 + half * 8;
    float4 o[2];
#pragma unroll
    for (int q = 0; q < 2; ++q) {
        o[q].x = acc[q * 4 + 0] * 256.0f + bp[q * 4 + 0];
        o[q].y = acc[q * 4 + 1] * 256.0f + bp[q * 4 + 1];
        o[q].z = acc[q * 4 + 2] * 256.0f + bp[q * 4 + 2];
        o[q].w = acc[q * 4 + 3] * 256.0f + bp[q * 4 + 3];
    }
    float4* dst = (float4*)(outp + (size_t)d * 16 + half * 8);
    dst[0] = o[0];
    dst[1] = o[1];
}

extern "C" void kernel_launch(void* const* d_in, const int* in_sizes, int n_in,
                              void* d_out, int out_size, void* d_ws, size_t ws_size,
                              hipStream_t stream) {
    const float* h   = (const float*)d_in[0];
    const float* pos = (const float*)d_in[1];
    const int*   nbr = (const int*)d_in[2];
    const float* W0  = (const float*)d_in[3];
    const float* b0  = (const float*)d_in[4];
    const float* W1  = (const float*)d_in[5];
    const float* b1  = (const float*)d_in[6];
    const float* W2  = (const float*)d_in[7];
    const float* b2  = (const float*)d_in[8];

    const int N = NNODES;

    // ws: h1 (64 MiB) + P (64 MiB) = 128 MiB exactly.
    char* w = (char*)d_ws;
    __half* h1 = (__half*)w;                               // 67,108,864 B
    __half* P  = (__half*)(w + (size_t)67108864);          // 67,108,864 B
    __half* invd2 = (__half*)w;                            // 4 MiB, into dead h1

    // d_out doubles as scratch until reduce overwrites all of it (16 MiB).
    char* ob = (char*)d_out;
    __half* invd = (__half*)(ob + 0);                      // 4,194,304 B
    __half* h16  = (__half*)(ob + 4194304);                // 8,388,608 B
    __half* W0f  = (__half*)(ob + 12582912);               // 32,768 B
    __half* W1f  = (__half*)(ob + 12615680);               // 262,144 B
    __half* Wf2s = (__half*)(ob + 12877824);               // 32,768 B (end 12,910,592)

    // Fused prep: 16384 + 8192 + 64 + 512 + 64 = 25216 blocks.
    prep_all_kernel<<<25216, 256, 0, stream>>>(h, h16, pos, nbr, invd,
                                               W0, W0f, W1, W1f, W2, Wf2s);

    layer0_kernel<<<N / 128, 256, 0, stream>>>(h16, invd, nbr, W0f, b0, h1);
    layer1p_kernel<<<N / 64, 256, 0, stream>>>(h1, invd, nbr, W1f, Wf2s, b1, P);

    // h1 is dead now; move invd out of d_out before reduce writes d_out.
    (void)hipMemcpyAsync(invd2, invd, 4194304, hipMemcpyDeviceToDevice, stream);

    reduce_kernel<<<(N * 2) / 256, 256, 0, stream>>>(P, invd2, nbr, b2, (float*)d_out);
}